// Round 21
// baseline (349.798 us; speedup 1.0000x reference)
//
#include <hip/hip_runtime.h>
#include <hip/hip_bf16.h>
#include <cstdint>

#define D_IN 128
#define DK 32
#define NH 8
#define HD 256   // NH*DK

typedef __attribute__((ext_vector_type(8))) short short8;
typedef __attribute__((ext_vector_type(4))) float f32x4;
typedef _Float16 h2v __attribute__((ext_vector_type(2)));
typedef __attribute__((ext_vector_type(4))) unsigned int u32x4;

__device__ inline float u2f(unsigned int u) {
  union { unsigned int i; float f; } c; c.i = u; return c.f;
}
__device__ inline short f2bf(float f) {
  union { float f; unsigned int i; } c; c.f = f;
  unsigned int u = c.i;
  u = u + 0x7FFFu + ((u >> 16) & 1u);  // RNE
  return (short)(u >> 16);
}
__device__ inline short f2h(float f) {
  union { _Float16 h; short s; } c; c.h = (_Float16)f; return c.s;
}
__device__ inline h2v u2h2(unsigned int u) {
  union { unsigned int u; h2v h; } c; c.u = u; return c.h;
}
// DPP quad-perm (explicit lane selects; 0xB1=(1,0,3,2)=xor1, 0x4E=(2,3,0,1)=xor2)
#define DPPF(x, ctrl)                                                         \
  ({                                                                          \
    union { float f; int i; } _a, _r;                                         \
    _a.f = (x);                                                               \
    _r.i = __builtin_amdgcn_update_dpp(0, _a.i, (ctrl), 0xF, 0xF, true);      \
    _r.f;                                                                     \
  })

// ---------- prep B: Wcat[128][768] -> bf16 MFMA B-fragments (MFMA stays bf16) ----------
__global__ __launch_bounds__(256) void prep_w_kernel(
    const float* __restrict__ WQ, const float* __restrict__ WK,
    const float* __restrict__ WV, short8* __restrict__ Bbuf) {
  int ct = blockIdx.x;  // 0..47
  int t = threadIdx.x;
  int kt = t >> 6, L = t & 63;
  int col = ct * 16 + (L & 15);
  int type = col >> 8;
  const float* W = (type == 0) ? WQ : (type == 1) ? WK : WV;
  int head = (col & 255) >> 5;
  int kk = col & 31;
  int k0 = kt * 32 + ((L >> 4) << 3);
  short8 o;
  #pragma unroll
  for (int r = 0; r < 8; r++)
    o[r] = f2bf(W[head * (D_IN * DK) + (k0 + r) * DK + kk]);
  Bbuf[(size_t)(ct * 4 + kt) * 64 + L] = o;
}

// ---------- MFMA GEMM: head-major Qh/KVh in F16 (Qh PRE-SCALED by 1/sqrt(32)*log2e) ----------
// Qh[head][node][32] f16; KVh[head][node][64] f16 (128B rows: K32|V32).
__global__ __launch_bounds__(256) void gemm_qkv_kernel(
    const float* __restrict__ h, const short8* __restrict__ Bbuf,
    short* __restrict__ Qh, short* __restrict__ KVh,
    int nt_total, int n_node) {
  __shared__ float hs[16][132];
  __shared__ short lds[16][768];  // Q 0-255 | K 256-511 | V 512-767 (head-major), f16 bits
  int nt = blockIdx.x;
  int t = threadIdx.x;
  {
    const float4* h4 = (const float4*)(h + (size_t)nt * 16 * 128);
    float4 v0 = h4[t * 2], v1 = h4[t * 2 + 1];
    int node = t >> 4, dim = (t & 15) * 8;
    hs[node][dim + 0] = v0.x; hs[node][dim + 1] = v0.y;
    hs[node][dim + 2] = v0.z; hs[node][dim + 3] = v0.w;
    hs[node][dim + 4] = v1.x; hs[node][dim + 5] = v1.y;
    hs[node][dim + 6] = v1.z; hs[node][dim + 7] = v1.w;
  }
  __syncthreads();
  int w = t >> 6;
  int L = t & 63;
  int arow = L & 15, k0base = ((L >> 4) << 3);
  short8 afrag[4];
  #pragma unroll
  for (int kt = 0; kt < 4; kt++) {
    #pragma unroll
    for (int r = 0; r < 8; r++)
      afrag[kt][r] = f2bf(hs[arow][kt * 32 + k0base + r]);
  }
  f32x4 acc[12];
  #pragma unroll
  for (int c = 0; c < 12; c++) acc[c] = (f32x4){0.f, 0.f, 0.f, 0.f};
  #pragma unroll
  for (int kt = 0; kt < 4; kt++) {
    #pragma unroll
    for (int c = 0; c < 12; c++) {
      short8 b = Bbuf[(size_t)((w * 12 + c) * 4 + kt) * 64 + L];
      acc[c] = __builtin_amdgcn_mfma_f32_16x16x32_bf16(afrag[kt], b, acc[c], 0, 0, 0);
    }
  }
  int row0 = (L >> 4) << 2;
  int col0 = w * 192 + (L & 15);
  const float QSL = 0.25506966f;  // (1/sqrt(32)) * log2(e)
  #pragma unroll
  for (int c = 0; c < 12; c++) {
    float sc = ((w * 192 + c * 16) < 256) ? QSL : 1.f;  // Q cols pre-scaled
    #pragma unroll
    for (int r = 0; r < 4; r++)
      lds[row0 + r][col0 + c * 16] = f2h(acc[c][r] * sc);  // store f16 bits
  }
  __syncthreads();
  // Qh out
  #pragma unroll
  for (int j = 0; j < 2; j++) {
    int u = t + j * 256;
    int hh = u >> 6, r2 = (u >> 2) & 15, part = u & 3;
    float4 vdat = *(const float4*)&lds[r2][hh * 32 + part * 8];
    *(float4*)(Qh + ((size_t)hh * n_node + nt * 16 + r2) * 32 + part * 8) = vdat;
  }
  // KVh out
  #pragma unroll
  for (int j = 0; j < 4; j++) {
    int u = t + j * 256;
    int hh = u >> 7, r2 = (u >> 3) & 15, part = u & 7;
    int srccol = (part < 4) ? (256 + hh * 32 + part * 8)
                            : (512 + hh * 32 + (part - 4) * 8);
    float4 vdat = *(const float4*)&lds[r2][srccol];
    *(float4*)(KVh + ((size_t)hh * n_node + nt * 16 + r2) * 64 +
               ((part < 4) ? part * 8 : 32 + (part - 4) * 8)) = vdat;
  }
}

// ---------------- CSR build ----------------
__global__ void rank_kernel(const int* __restrict__ row, int n_edge,
                            int* __restrict__ cnt, int* __restrict__ rank) {
  int i = blockIdx.x * blockDim.x + threadIdx.x;
  if (i < n_edge) rank[i] = atomicAdd(&cnt[row[i]], 1);
}

__global__ __launch_bounds__(256) void scan1_kernel(
    const int* __restrict__ cnt, int n, int* __restrict__ exc,
    int* __restrict__ bsum) {
  __shared__ int s[256];
  int gid = blockIdx.x * 256 + threadIdx.x;
  int v = (gid < n) ? cnt[gid] : 0;
  s[threadIdx.x] = v;
  __syncthreads();
  #pragma unroll
  for (int off = 1; off < 256; off <<= 1) {
    int t = (threadIdx.x >= off) ? s[threadIdx.x - off] : 0;
    __syncthreads();
    s[threadIdx.x] += t;
    __syncthreads();
  }
  if (gid < n) exc[gid] = s[threadIdx.x] - v;
  if (threadIdx.x == 255) bsum[blockIdx.x] = s[255];
}

__global__ __launch_bounds__(256) void scan2_kernel(int* __restrict__ bsum,
                                                    int nb) {
  __shared__ int s[256];
  int v = (threadIdx.x < nb) ? bsum[threadIdx.x] : 0;
  s[threadIdx.x] = v;
  __syncthreads();
  #pragma unroll
  for (int off = 1; off < 256; off <<= 1) {
    int t = (threadIdx.x >= off) ? s[threadIdx.x - off] : 0;
    __syncthreads();
    s[threadIdx.x] += t;
    __syncthreads();
  }
  if (threadIdx.x < nb) bsum[threadIdx.x] = s[threadIdx.x] - v;
}

__global__ __launch_bounds__(256) void scan3_kernel(
    int* __restrict__ exc, const int* __restrict__ bsum, int n, int n_edge) {
  int gid = blockIdx.x * 256 + threadIdx.x;
  if (gid < n) exc[gid] = exc[gid] + bsum[blockIdx.x];
  if (gid == 0) exc[n] = n_edge;
}

__global__ void scatter_kernel(const int* __restrict__ row,
                               const int* __restrict__ col,
                               const int* __restrict__ rank, int n_edge,
                               const int* __restrict__ offsets,
                               int* __restrict__ col_sorted) {
  int i = blockIdx.x * blockDim.x + threadIdx.x;
  if (i < n_edge) col_sorted[offsets[row[i]] + rank[i]] = col[i];
}

// ---------------- Attention: quad-per-edge + non-temporal streaming hints ----------------
// head = blockIdx%8 (XCD-pinned 6.4MB KVh slice; FETCH-halving proven r11/r12).
// Lane l serves edge base+(l>>2), dim-slice (l&3)*8..+7. Per iter (16 edges):
// load K-half + V-half of OWN edge's 128B row (same line), 4 fdot2, quad
// xor1/xor2 (DPP) -> full 32-dim logit in ALL 4 lanes, 1 exp2, own V-slice.
// r20/21: col_sorted/Qh loads and out stores are NON-TEMPORAL -> they stop
// evicting KVh lines from the 4MB per-XCD L2 (KVh is the only reused data:
// ~32 re-reads/line; col/Qh are read once per head, out is write-once).
// (ext-vector types for the builtins: HIP float4 struct is rejected.)
#define QPROC(rk, rv, vld)                                                   \
  {                                                                          \
    h2v k0 = u2h2(rk.x), k1 = u2h2(rk.y), k2 = u2h2(rk.z), k3 = u2h2(rk.w);  \
    float d = __builtin_amdgcn_fdot2(k3, q3, 0.f, false);                    \
    d = __builtin_amdgcn_fdot2(k2, q2, d, false);                            \
    d = __builtin_amdgcn_fdot2(k1, q1, d, false);                            \
    d = __builtin_amdgcn_fdot2(k0, q0, d, false);                            \
    d += DPPF(d, 0xB1);              /* xor1: quad_perm(1,0,3,2) */          \
    d += DPPF(d, 0x4E);              /* xor2: quad_perm(2,3,0,1) */          \
    float p = (vld) ? exp2f(d) : 0.f;                                        \
    dn += p;                                                                 \
    h2v v0 = u2h2(rv.x), v1 = u2h2(rv.y), v2 = u2h2(rv.z), v3 = u2h2(rv.w);  \
    a0 = fmaf(p, (float)v0[0], a0); a1 = fmaf(p, (float)v0[1], a1);          \
    a2 = fmaf(p, (float)v1[0], a2); a3 = fmaf(p, (float)v1[1], a3);          \
    a4 = fmaf(p, (float)v2[0], a4); a5 = fmaf(p, (float)v2[1], a5);          \
    a6 = fmaf(p, (float)v3[0], a6); a7 = fmaf(p, (float)v3[1], a7);          \
  }

__global__ __launch_bounds__(256) void attn_kernel(
    const short* __restrict__ Qh, const short* __restrict__ KVh,
    const int* __restrict__ offsets, const int* __restrict__ col_sorted,
    float* __restrict__ out, int n_node) {
  int head = blockIdx.x & 7;   // XCD-pinned
  int grp = blockIdx.x >> 3;
  int wv = threadIdx.x >> 6;
  int lane = threadIdx.x & 63;
  int eslot = lane >> 2;  // edge slot 0..15
  int q4 = lane & 3;      // dim slice: dims q4*8 .. q4*8+7
  int node = grp * 4 + wv;
  if (node >= n_node) return;
  int start = offsets[node], end = offsets[node + 1];

  if (end <= start) {
    if (lane < 4) {
      float* op = out + (size_t)node * HD + head * 32 + q4 * 8;
      f32x4 z = (f32x4){0.f, 0.f, 0.f, 0.f};
      __builtin_nontemporal_store(z, (f32x4*)op);
      __builtin_nontemporal_store(z, (f32x4*)(op + 4));
    }
    return;
  }

  // q slice (q4): 8 f16 kept PACKED (pre-scaled at GEMM); non-temporal read
  h2v q0, q1, q2, q3;
  {
    u32x4 qr = __builtin_nontemporal_load((const u32x4*)((const char*)(Qh +
                ((size_t)head * n_node + node) * 32) + q4 * 16));
    q0 = u2h2(qr.x); q1 = u2h2(qr.y); q2 = u2h2(qr.z); q3 = u2h2(qr.w);
  }
  float dn = 0.f;
  float a0 = 0.f, a1 = 0.f, a2 = 0.f, a3 = 0.f;
  float a4 = 0.f, a5 = 0.f, a6 = 0.f, a7 = 0.f;

  const char* kvb = (const char*)KVh + (size_t)head * n_node * 128;
  unsigned int qoff = (unsigned int)q4 << 4;

  for (int base = start; base < end; base += 32) {
    int i0 = base + eslot, i1 = base + 16 + eslot;
    bool v0 = i0 < end, v1 = i1 < end;
    int c0 = __builtin_nontemporal_load(col_sorted + (v0 ? i0 : start));
    int c1 = __builtin_nontemporal_load(col_sorted + (v1 ? i1 : start));
    unsigned int b0 = ((unsigned int)c0 << 7) + qoff;
    unsigned int b1 = ((unsigned int)c1 << 7) + qoff;
    uint4 rk0 = *(const uint4*)(kvb + b0);
    uint4 rv0 = *(const uint4*)(kvb + b0 + 64);
    uint4 rk1 = *(const uint4*)(kvb + b1);
    uint4 rv1 = *(const uint4*)(kvb + b1 + 64);
    QPROC(rk0, rv0, v0);
    QPROC(rk1, rv1, v1);
  }

  // merge the 16 edge slots: xor over lane bits 2..5 (once per node)
  dn += __shfl_xor(dn, 4); dn += __shfl_xor(dn, 8);
  dn += __shfl_xor(dn, 16); dn += __shfl_xor(dn, 32);
#define MRG(x)                                                               \
  x += __shfl_xor(x, 4); x += __shfl_xor(x, 8);                              \
  x += __shfl_xor(x, 16); x += __shfl_xor(x, 32);
  MRG(a0) MRG(a1) MRG(a2) MRG(a3) MRG(a4) MRG(a5) MRG(a6) MRG(a7)

  float inv = 1.f / dn;
  if (lane < 4) {  // lane q4 holds dims q4*8..q4*8+7
    float* op = out + (size_t)node * HD + head * 32 + q4 * 8;
    f32x4 o0 = (f32x4){a0 * inv, a1 * inv, a2 * inv, a3 * inv};
    f32x4 o1 = (f32x4){a4 * inv, a5 * inv, a6 * inv, a7 * inv};
    __builtin_nontemporal_store(o0, (f32x4*)op);
    __builtin_nontemporal_store(o1, (f32x4*)(op + 4));
  }
}

extern "C" void kernel_launch(void* const* d_in, const int* in_sizes, int n_in,
                              void* d_out, int out_size, void* d_ws,
                              size_t ws_size, hipStream_t stream) {
  const float* h = (const float*)d_in[0];
  const int* edge = (const int*)d_in[1];
  const float* WQ = (const float*)d_in[2];
  const float* WK = (const float*)d_in[3];
  const float* WV = (const float*)d_in[4];
  float* out = (float*)d_out;

  int n_node = in_sizes[0] / D_IN;
  int n_edge = in_sizes[1] / 2;
  const int* row = edge;
  const int* col = edge + n_edge;

  char* ws = (char*)d_ws;
  size_t off = 0;
  auto alloc = [&](size_t bytes) {
    void* p = ws + off;
    off += (bytes + 255) & ~(size_t)255;
    return p;
  };
  int nt_total = (n_node + 15) / 16;  // 3125 (50000 = 3125*16 exactly)
  short* Qh = (short*)alloc((size_t)NH * n_node * 32 * 2);
  short* KVh = (short*)alloc((size_t)NH * n_node * 64 * 2);
  short8* Bbuf = (short8*)alloc((size_t)48 * 4 * 64 * 16);
  int* col_sorted = (int*)alloc((size_t)n_edge * 4);
  int* rank = (int*)alloc((size_t)n_edge * 4);
  int* cnt = (int*)alloc((size_t)n_node * 4);
  int* offsets = (int*)alloc((size_t)(n_node + 1) * 4);
  int* bsum = (int*)alloc(256 * 4);

  hipMemsetAsync(cnt, 0, (size_t)n_node * 4, stream);

  prep_w_kernel<<<48, 256, 0, stream>>>(WQ, WK, WV, Bbuf);
  gemm_qkv_kernel<<<nt_total, 256, 0, stream>>>(h, Bbuf, Qh, KVh, nt_total,
                                                n_node);

  int nb_e = (n_edge + 255) / 256;
  rank_kernel<<<nb_e, 256, 0, stream>>>(row, n_edge, cnt, rank);

  int nb = (n_node + 255) / 256;
  scan1_kernel<<<nb, 256, 0, stream>>>(cnt, n_node, offsets, bsum);
  scan2_kernel<<<1, 256, 0, stream>>>(bsum, nb);
  scan3_kernel<<<nb, 256, 0, stream>>>(offsets, bsum, n_node, n_edge);

  scatter_kernel<<<nb_e, 256, 0, stream>>>(row, col, rank, n_edge, offsets,
                                           col_sorted);

  attn_kernel<<<((n_node + 3) / 4) * 8, 256, 0, stream>>>(
      Qh, KVh, offsets, col_sorted, out, n_node);
}

// Round 22
// 316.139 us; speedup vs baseline: 1.1065x; 1.1065x over previous
//
#include <hip/hip_runtime.h>
#include <hip/hip_bf16.h>
#include <cstdint>

#define D_IN 128
#define DK 32
#define NH 8
#define HD 256   // NH*DK

typedef __attribute__((ext_vector_type(8))) short short8;
typedef __attribute__((ext_vector_type(4))) float f32x4;
typedef _Float16 h2v __attribute__((ext_vector_type(2)));

__device__ inline float u2f(unsigned int u) {
  union { unsigned int i; float f; } c; c.i = u; return c.f;
}
__device__ inline short f2bf(float f) {
  union { float f; unsigned int i; } c; c.f = f;
  unsigned int u = c.i;
  u = u + 0x7FFFu + ((u >> 16) & 1u);  // RNE
  return (short)(u >> 16);
}
__device__ inline short f2h(float f) {
  union { _Float16 h; short s; } c; c.h = (_Float16)f; return c.s;
}
__device__ inline h2v u2h2(unsigned int u) {
  union { unsigned int u; h2v h; } c; c.u = u; return c.h;
}
// DPP quad-perm (explicit lane selects; 0xB1=(1,0,3,2)=xor1, 0x4E=(2,3,0,1)=xor2)
#define DPPF(x, ctrl)                                                         \
  ({                                                                          \
    union { float f; int i; } _a, _r;                                         \
    _a.f = (x);                                                               \
    _r.i = __builtin_amdgcn_update_dpp(0, _a.i, (ctrl), 0xF, 0xF, true);      \
    _r.f;                                                                     \
  })

// ---------- prep B: Wcat[128][768] -> bf16 MFMA B-fragments (MFMA stays bf16) ----------
__global__ __launch_bounds__(256) void prep_w_kernel(
    const float* __restrict__ WQ, const float* __restrict__ WK,
    const float* __restrict__ WV, short8* __restrict__ Bbuf) {
  int ct = blockIdx.x;  // 0..47
  int t = threadIdx.x;
  int kt = t >> 6, L = t & 63;
  int col = ct * 16 + (L & 15);
  int type = col >> 8;
  const float* W = (type == 0) ? WQ : (type == 1) ? WK : WV;
  int head = (col & 255) >> 5;
  int kk = col & 31;
  int k0 = kt * 32 + ((L >> 4) << 3);
  short8 o;
  #pragma unroll
  for (int r = 0; r < 8; r++)
    o[r] = f2bf(W[head * (D_IN * DK) + (k0 + r) * DK + kk]);
  Bbuf[(size_t)(ct * 4 + kt) * 64 + L] = o;
}

// ---------- MFMA GEMM: head-major Qh/KVh in F16 (Qh PRE-SCALED by 1/sqrt(32)*log2e) ----------
// Qh[head][node][32] f16; KVh[head][node][64] f16 (128B rows: K32|V32).
__global__ __launch_bounds__(256) void gemm_qkv_kernel(
    const float* __restrict__ h, const short8* __restrict__ Bbuf,
    short* __restrict__ Qh, short* __restrict__ KVh,
    int nt_total, int n_node) {
  __shared__ float hs[16][132];
  __shared__ short lds[16][768];  // Q 0-255 | K 256-511 | V 512-767 (head-major), f16 bits
  int nt = blockIdx.x;
  int t = threadIdx.x;
  {
    const float4* h4 = (const float4*)(h + (size_t)nt * 16 * 128);
    float4 v0 = h4[t * 2], v1 = h4[t * 2 + 1];
    int node = t >> 4, dim = (t & 15) * 8;
    hs[node][dim + 0] = v0.x; hs[node][dim + 1] = v0.y;
    hs[node][dim + 2] = v0.z; hs[node][dim + 3] = v0.w;
    hs[node][dim + 4] = v1.x; hs[node][dim + 5] = v1.y;
    hs[node][dim + 6] = v1.z; hs[node][dim + 7] = v1.w;
  }
  __syncthreads();
  int w = t >> 6;
  int L = t & 63;
  int arow = L & 15, k0base = ((L >> 4) << 3);
  short8 afrag[4];
  #pragma unroll
  for (int kt = 0; kt < 4; kt++) {
    #pragma unroll
    for (int r = 0; r < 8; r++)
      afrag[kt][r] = f2bf(hs[arow][kt * 32 + k0base + r]);
  }
  f32x4 acc[12];
  #pragma unroll
  for (int c = 0; c < 12; c++) acc[c] = (f32x4){0.f, 0.f, 0.f, 0.f};
  #pragma unroll
  for (int kt = 0; kt < 4; kt++) {
    #pragma unroll
    for (int c = 0; c < 12; c++) {
      short8 b = Bbuf[(size_t)((w * 12 + c) * 4 + kt) * 64 + L];
      acc[c] = __builtin_amdgcn_mfma_f32_16x16x32_bf16(afrag[kt], b, acc[c], 0, 0, 0);
    }
  }
  int row0 = (L >> 4) << 2;
  int col0 = w * 192 + (L & 15);
  const float QSL = 0.25506966f;  // (1/sqrt(32)) * log2(e)
  #pragma unroll
  for (int c = 0; c < 12; c++) {
    float sc = ((w * 192 + c * 16) < 256) ? QSL : 1.f;  // Q cols pre-scaled
    #pragma unroll
    for (int r = 0; r < 4; r++)
      lds[row0 + r][col0 + c * 16] = f2h(acc[c][r] * sc);  // store f16 bits
  }
  __syncthreads();
  // Qh out
  #pragma unroll
  for (int j = 0; j < 2; j++) {
    int u = t + j * 256;
    int hh = u >> 6, r2 = (u >> 2) & 15, part = u & 3;
    float4 vdat = *(const float4*)&lds[r2][hh * 32 + part * 8];
    *(float4*)(Qh + ((size_t)hh * n_node + nt * 16 + r2) * 32 + part * 8) = vdat;
  }
  // KVh out
  #pragma unroll
  for (int j = 0; j < 4; j++) {
    int u = t + j * 256;
    int hh = u >> 7, r2 = (u >> 3) & 15, part = u & 7;
    int srccol = (part < 4) ? (256 + hh * 32 + part * 8)
                            : (512 + hh * 32 + (part - 4) * 8);
    float4 vdat = *(const float4*)&lds[r2][srccol];
    *(float4*)(KVh + ((size_t)hh * n_node + nt * 16 + r2) * 64 +
               ((part < 4) ? part * 8 : 32 + (part - 4) * 8)) = vdat;
  }
}

// ---------------- CSR build ----------------
__global__ void rank_kernel(const int* __restrict__ row, int n_edge,
                            int* __restrict__ cnt, int* __restrict__ rank) {
  int i = blockIdx.x * blockDim.x + threadIdx.x;
  if (i < n_edge) rank[i] = atomicAdd(&cnt[row[i]], 1);
}

__global__ __launch_bounds__(256) void scan1_kernel(
    const int* __restrict__ cnt, int n, int* __restrict__ exc,
    int* __restrict__ bsum) {
  __shared__ int s[256];
  int gid = blockIdx.x * 256 + threadIdx.x;
  int v = (gid < n) ? cnt[gid] : 0;
  s[threadIdx.x] = v;
  __syncthreads();
  #pragma unroll
  for (int off = 1; off < 256; off <<= 1) {
    int t = (threadIdx.x >= off) ? s[threadIdx.x - off] : 0;
    __syncthreads();
    s[threadIdx.x] += t;
    __syncthreads();
  }
  if (gid < n) exc[gid] = s[threadIdx.x] - v;
  if (threadIdx.x == 255) bsum[blockIdx.x] = s[255];
}

__global__ __launch_bounds__(256) void scan2_kernel(int* __restrict__ bsum,
                                                    int nb) {
  __shared__ int s[256];
  int v = (threadIdx.x < nb) ? bsum[threadIdx.x] : 0;
  s[threadIdx.x] = v;
  __syncthreads();
  #pragma unroll
  for (int off = 1; off < 256; off <<= 1) {
    int t = (threadIdx.x >= off) ? s[threadIdx.x - off] : 0;
    __syncthreads();
    s[threadIdx.x] += t;
    __syncthreads();
  }
  if (threadIdx.x < nb) bsum[threadIdx.x] = s[threadIdx.x] - v;
}

__global__ __launch_bounds__(256) void scan3_kernel(
    int* __restrict__ exc, const int* __restrict__ bsum, int n, int n_edge) {
  int gid = blockIdx.x * 256 + threadIdx.x;
  if (gid < n) exc[gid] = exc[gid] + bsum[blockIdx.x];
  if (gid == 0) exc[n] = n_edge;
}

__global__ void scatter_kernel(const int* __restrict__ row,
                               const int* __restrict__ col,
                               const int* __restrict__ rank, int n_edge,
                               const int* __restrict__ offsets,
                               int* __restrict__ col_sorted) {
  int i = blockIdx.x * blockDim.x + threadIdx.x;
  if (i < n_edge) col_sorted[offsets[row[i]] + rank[i]] = col[i];
}

// ---------------- Attention: QUAD-per-edge, zero wasted lane-work (r19 best) ----------------
// head = blockIdx%8 (XCD-pinned 6.4MB KVh slice; FETCH-halving proven r11/r12).
// Lane l serves edge base+(l>>2), dim-slice (l&3)*8..+7. Per iter (16 edges):
// load K-half + V-half of OWN edge's 128B row (same line), 4 fdot2, quad
// xor1/xor2 (DPP) -> full 32-dim logit in ALL 4 lanes (no transfer shfl),
// 1 exp2, accumulate own V-slice. Epilogue merges over lane bits 2..5.
#define QPROC(rk, rv, vld)                                                   \
  {                                                                          \
    h2v k0 = u2h2(rk.x), k1 = u2h2(rk.y), k2 = u2h2(rk.z), k3 = u2h2(rk.w);  \
    float d = __builtin_amdgcn_fdot2(k3, q3, 0.f, false);                    \
    d = __builtin_amdgcn_fdot2(k2, q2, d, false);                            \
    d = __builtin_amdgcn_fdot2(k1, q1, d, false);                            \
    d = __builtin_amdgcn_fdot2(k0, q0, d, false);                            \
    d += DPPF(d, 0xB1);              /* xor1: quad_perm(1,0,3,2) */          \
    d += DPPF(d, 0x4E);              /* xor2: quad_perm(2,3,0,1) */          \
    float p = (vld) ? exp2f(d) : 0.f;                                        \
    dn += p;                                                                 \
    h2v v0 = u2h2(rv.x), v1 = u2h2(rv.y), v2 = u2h2(rv.z), v3 = u2h2(rv.w);  \
    a0 = fmaf(p, (float)v0[0], a0); a1 = fmaf(p, (float)v0[1], a1);          \
    a2 = fmaf(p, (float)v1[0], a2); a3 = fmaf(p, (float)v1[1], a3);          \
    a4 = fmaf(p, (float)v2[0], a4); a5 = fmaf(p, (float)v2[1], a5);          \
    a6 = fmaf(p, (float)v3[0], a6); a7 = fmaf(p, (float)v3[1], a7);          \
  }

__global__ __launch_bounds__(256) void attn_kernel(
    const short* __restrict__ Qh, const short* __restrict__ KVh,
    const int* __restrict__ offsets, const int* __restrict__ col_sorted,
    float* __restrict__ out, int n_node) {
  int head = blockIdx.x & 7;   // XCD-pinned
  int grp = blockIdx.x >> 3;
  int wv = threadIdx.x >> 6;
  int lane = threadIdx.x & 63;
  int eslot = lane >> 2;  // edge slot 0..15
  int q4 = lane & 3;      // dim slice: dims q4*8 .. q4*8+7
  int node = grp * 4 + wv;
  if (node >= n_node) return;
  int start = offsets[node], end = offsets[node + 1];

  if (end <= start) {
    if (lane < 4) {
      float* op = out + (size_t)node * HD + head * 32 + q4 * 8;
      float4 z = make_float4(0.f, 0.f, 0.f, 0.f);
      *(float4*)op = z;
      *(float4*)(op + 4) = z;
    }
    return;
  }

  // q slice (q4): 8 f16 kept PACKED (pre-scaled at GEMM)
  h2v q0, q1, q2, q3;
  {
    uint4 qr = *(const uint4*)((const char*)(Qh +
                ((size_t)head * n_node + node) * 32) + q4 * 16);
    q0 = u2h2(qr.x); q1 = u2h2(qr.y); q2 = u2h2(qr.z); q3 = u2h2(qr.w);
  }
  float dn = 0.f;
  float a0 = 0.f, a1 = 0.f, a2 = 0.f, a3 = 0.f;
  float a4 = 0.f, a5 = 0.f, a6 = 0.f, a7 = 0.f;

  const char* kvb = (const char*)KVh + (size_t)head * n_node * 128;
  unsigned int qoff = (unsigned int)q4 << 4;

  for (int base = start; base < end; base += 32) {
    int i0 = base + eslot, i1 = base + 16 + eslot;
    bool v0 = i0 < end, v1 = i1 < end;
    int c0 = col_sorted[v0 ? i0 : start];
    int c1 = col_sorted[v1 ? i1 : start];
    unsigned int b0 = ((unsigned int)c0 << 7) + qoff;
    unsigned int b1 = ((unsigned int)c1 << 7) + qoff;
    uint4 rk0 = *(const uint4*)(kvb + b0);
    uint4 rv0 = *(const uint4*)(kvb + b0 + 64);
    uint4 rk1 = *(const uint4*)(kvb + b1);
    uint4 rv1 = *(const uint4*)(kvb + b1 + 64);
    QPROC(rk0, rv0, v0);
    QPROC(rk1, rv1, v1);
  }

  // merge the 16 edge slots: xor over lane bits 2..5 (once per node)
  dn += __shfl_xor(dn, 4); dn += __shfl_xor(dn, 8);
  dn += __shfl_xor(dn, 16); dn += __shfl_xor(dn, 32);
#define MRG(x)                                                               \
  x += __shfl_xor(x, 4); x += __shfl_xor(x, 8);                              \
  x += __shfl_xor(x, 16); x += __shfl_xor(x, 32);
  MRG(a0) MRG(a1) MRG(a2) MRG(a3) MRG(a4) MRG(a5) MRG(a6) MRG(a7)

  float inv = 1.f / dn;
  if (lane < 4) {  // lane q4 holds dims q4*8..q4*8+7
    float* op = out + (size_t)node * HD + head * 32 + q4 * 8;
    float4 o0 = make_float4(a0 * inv, a1 * inv, a2 * inv, a3 * inv);
    float4 o1 = make_float4(a4 * inv, a5 * inv, a6 * inv, a7 * inv);
    *(float4*)op = o0;
    *(float4*)(op + 4) = o1;
  }
}

extern "C" void kernel_launch(void* const* d_in, const int* in_sizes, int n_in,
                              void* d_out, int out_size, void* d_ws,
                              size_t ws_size, hipStream_t stream) {
  const float* h = (const float*)d_in[0];
  const int* edge = (const int*)d_in[1];
  const float* WQ = (const float*)d_in[2];
  const float* WK = (const float*)d_in[3];
  const float* WV = (const float*)d_in[4];
  float* out = (float*)d_out;

  int n_node = in_sizes[0] / D_IN;
  int n_edge = in_sizes[1] / 2;
  const int* row = edge;
  const int* col = edge + n_edge;

  char* ws = (char*)d_ws;
  size_t off = 0;
  auto alloc = [&](size_t bytes) {
    void* p = ws + off;
    off += (bytes + 255) & ~(size_t)255;
    return p;
  };
  int nt_total = (n_node + 15) / 16;  // 3125 (50000 = 3125*16 exactly)
  short* Qh = (short*)alloc((size_t)NH * n_node * 32 * 2);
  short* KVh = (short*)alloc((size_t)NH * n_node * 64 * 2);
  short8* Bbuf = (short8*)alloc((size_t)48 * 4 * 64 * 16);
  int* col_sorted = (int*)alloc((size_t)n_edge * 4);
  int* rank = (int*)alloc((size_t)n_edge * 4);
  int* cnt = (int*)alloc((size_t)n_node * 4);
  int* offsets = (int*)alloc((size_t)(n_node + 1) * 4);
  int* bsum = (int*)alloc(256 * 4);

  hipMemsetAsync(cnt, 0, (size_t)n_node * 4, stream);

  prep_w_kernel<<<48, 256, 0, stream>>>(WQ, WK, WV, Bbuf);
  gemm_qkv_kernel<<<nt_total, 256, 0, stream>>>(h, Bbuf, Qh, KVh, nt_total,
                                                n_node);

  int nb_e = (n_edge + 255) / 256;
  rank_kernel<<<nb_e, 256, 0, stream>>>(row, n_edge, cnt, rank);

  int nb = (n_node + 255) / 256;
  scan1_kernel<<<nb, 256, 0, stream>>>(cnt, n_node, offsets, bsum);
  scan2_kernel<<<1, 256, 0, stream>>>(bsum, nb);
  scan3_kernel<<<nb, 256, 0, stream>>>(offsets, bsum, n_node, n_edge);

  scatter_kernel<<<nb_e, 256, 0, stream>>>(row, col, rank, n_edge, offsets,
                                           col_sorted);

  attn_kernel<<<((n_node + 3) / 4) * 8, 256, 0, stream>>>(
      Qh, KVh, offsets, col_sorted, out, n_node);
}